// Round 14
// baseline (138.877 us; speedup 1.0000x reference)
//
#include <hip/hip_runtime.h>

// SimpleDiagonalRNN: h_t = a*h_{t-1} + x_t, a = 1 - relu(w), x [8,4096,512] f32.
//
// Correctness model (stable since r0):
//  * a = 1 - relu(w) <= 1 always; ~2% of channels have a < -1 -> reference
//    diverges to +/-inf; pass criterion tolerates any FINITE value there
//    (failure mode is NaN from same-sign inf - inf). Output must be finite.
//  * Clamp at +/-1e15 on EVERY product/FMA: |a|<~5, all states <=1e15 ->
//    every intermediate <= ~2e30 << FLT_MAX. No inf formed -> no NaN.
//  * For contracting channels (|a|<=1) the clamp never fires -> all parallel
//    re-associations are exact mod FP rounding (r4/r8/r11/r12/r13 passed).
//
// Perf history / model:
//  * dur_us ~= 66-72us harness overhead (poison fills) + kernel total.
//  * r8/r11/r12/r13: FOUR different structures all converge to 52-54us at
//    2.4-2.9 TB/s with VALUBusy ~6%. r13 killed the spill theory: VGPR=36,
//    no arrays, yet WRITE still 87MB (+20 over the 67MB out).
//  * DIAGNOSIS: 16-channel d-tiles = 64B = HALF a 128B cache line. Every
//    wave touches 8 scattered half-lines -> line-granular HBM machinery
//    moves ~2x useful bytes on stores (+20MB write amp, measured) and
//    wastes half of every in-flight line on loads -> effective rate
//    ~2.5-2.9 TB/s = half the ~5-6 TB/s line rate. r3's contiguous-row
//    k_final measured clean 67.6MB writes (r1) -- layout, not structure.
//  * r14 (this): SAME verified 3-phase in-block scan, 32-channel tiles
//    (= exactly one 128B line). 128 blocks x 1024 thr; per wave each
//    8-lane cluster = one full line; 8 full lines per load instr.
//    CL=32, P2 = KS over 128 aggregates (2 windows x 8 groups = 16 waves).
//    Discriminating experiment: granularity-bound -> kernel ~30-36us,
//    WRITE ~67MB. Null (clean WRITE, still ~52us) -> in-flight x CU-count
//    bound -> next round reverts to two-dispatch contiguous-row shape.

#define RB 8
#define RT 4096
#define RD 512
#define DG (RD / 4)      // 128 float4 groups over d
#define TG 8             // float4 groups per tile (32 ch = 128B = 1 line)
#define NTL (DG / TG)    // 16 tiles
#define CL 32            // timesteps per chunk
#define NC (RT / CL)     // 128 chunks per block
#define TPB 1024         // 16 waves
#define PF 4             // prefetch batch
#define HB 1e15f

typedef float f32x4 __attribute__((ext_vector_type(4)));

__device__ __forceinline__ float sclamp(float v) {
    return fminf(fmaxf(v, -HB), HB);
}
__device__ __forceinline__ f32x4 sclamp4(f32x4 v) {
    v.x = sclamp(v.x); v.y = sclamp(v.y);
    v.z = sclamp(v.z); v.w = sclamp(v.w);
    return v;
}
__device__ __forceinline__ f32x4 ld4(const float4* __restrict__ p) {
    return *(const f32x4* __restrict__)p;
}
__device__ __forceinline__ f32x4 shfl4(f32x4 v, int src) {
    f32x4 r;
    r.x = __shfl(v.x, src, 64);
    r.y = __shfl(v.y, src, 64);
    r.z = __shfl(v.z, src, 64);
    r.w = __shfl(v.w, src, 64);
    return r;
}
__device__ __forceinline__ f32x4 relu_decay(float4 wq) {
    f32x4 a;
    a.x = 1.0f - fmaxf(wq.x, 0.0f);
    a.y = 1.0f - fmaxf(wq.y, 0.0f);
    a.z = 1.0f - fmaxf(wq.z, 0.0f);
    a.w = 1.0f - fmaxf(wq.w, 0.0f);
    return a;
}

// One block per (b, 32-channel tile): grid 128, 1024 threads (16 waves).
// Thread map (P1/P3): g = tid&7 (float4 within tile), c = tid>>3 (chunk).
// Wave-level: 8-lane cluster (g=0..7, fixed c) = 128B contiguous = 1 line.
__global__ void __launch_bounds__(TPB, 4)
rnn_fused3(const float4* __restrict__ x4, const float4* __restrict__ w4,
           float4* __restrict__ out4) {
    const int tid = threadIdx.x;
    const int g   = tid & (TG - 1);
    const int c   = tid >> 3;            // 0..127

    const int bid  = blockIdx.x;
    const int b    = bid >> 4;           // 0..7
    const int tile = bid & (NTL - 1);    // 0..15

    const f32x4 A1 = relu_decay(w4[tile * TG + g]);

    // LDS: [chunk][group] padded to 9 to break bank alignment.
    __shared__ f32x4 Wagg[NC * 9];       // chunk aggregates   [c*9+g]
    __shared__ f32x4 CI[NC * 9];         // chunk carry-ins    [c*9+g]
    __shared__ f32x4 WinAgg[2 * 9];      // window aggregates  [q*9+g]

    const size_t base = ((size_t)b * RT + (size_t)c * CL) * DG
                      + (size_t)(tile * TG + g);
    const float4* __restrict__ xb = x4 + base;

    // ---- Phase 1: aggregate-only chunk scan, PF=4 two-batch pipeline ----
    {
        f32x4 v[PF];
#pragma unroll
        for (int k = 0; k < PF; ++k) v[k] = ld4(xb + (size_t)k * DG);
        f32x4 h = {0.f, 0.f, 0.f, 0.f};
#pragma unroll
        for (int bb = 0; bb < CL; bb += PF) {
            f32x4 n[PF];
            if (bb + PF < CL) {          // compile-time (fully unrolled)
#pragma unroll
                for (int k = 0; k < PF; ++k)
                    n[k] = ld4(xb + (size_t)(bb + PF + k) * DG);
            }
#pragma unroll
            for (int k = 0; k < PF; ++k) h = sclamp4(A1 * h + v[k]);
            if (bb + PF < CL) {
#pragma unroll
                for (int k = 0; k < PF; ++k) v[k] = n[k];
            }
        }
        Wagg[c * 9 + g] = h;             // chunk-local end state
    }
    __syncthreads();

    // ---- Phase 2: scan over 128 chunk aggregates (16 waves: g2 x q) ----
    {
        const int w  = tid >> 6;         // wave 0..15
        const int l  = tid & 63;
        const int g2 = w & (TG - 1);     // group 0..7
        const int q  = w >> 3;           // window 0..1 (64 chunks each)
        const int cc = q * 64 + l;       // this lane's chunk

        // B = a^CL for group g2 (w4 is L1-hot).
        f32x4 B = relu_decay(w4[tile * TG + g2]);
#pragma unroll
        for (int i = 0; i < 5; ++i) B = sclamp4(B * B);   // B = a^32

        f32x4 S = Wagg[cc * 9 + g2];
        // Kogge-Stone inclusive over 64 lanes; multiplier B^s lane-uniform.
        f32x4 M = B;
#pragma unroll
        for (int s = 1; s < 64; s <<= 1) {
            f32x4 t = shfl4(S, l >= s ? l - s : l);
            S = (l >= s) ? sclamp4(M * t + S) : S;
            M = sclamp4(M * M);
        }
        // After loop M = B^64 (window aggregate multiplier).
        if (l == 63) WinAgg[q * 9 + g2] = S;
        __syncthreads();

        // Cross-window carry: window 1 is entered with window 0's aggregate.
        f32x4 WC = {0.f, 0.f, 0.f, 0.f};
        if (q == 1) WC = WinAgg[0 * 9 + g2];
        // Full inclusive state S_cc = S + B^(l+1) * WC.
        const int n = l + 1;             // 1..64
        f32x4 P = {1.f, 1.f, 1.f, 1.f};
        f32x4 mm = B;
#pragma unroll
        for (int k = 0; k < 7; ++k) {
            if ((n >> k) & 1) P = sclamp4(P * mm);
            mm = sclamp4(mm * mm);
        }
        f32x4 Sf = sclamp4(S + P * WC);
        // Carry-in for chunk cc+1 is S_cc; chunk 0 gets 0.
        if (cc < NC - 1) CI[(cc + 1) * 9 + g2] = Sf;
        if (cc == 0)     CI[0 * 9 + g2] = (f32x4){0.f, 0.f, 0.f, 0.f};
    }
    __syncthreads();

    // ---- Phase 3: replay chunk from (L2/L3-hot) x with true carry-in ----
    {
        float4* __restrict__ ob = out4 + base;
        f32x4 h = CI[c * 9 + g];         // state entering this chunk
        f32x4 v[PF];
#pragma unroll
        for (int k = 0; k < PF; ++k) v[k] = ld4(xb + (size_t)k * DG);
#pragma unroll
        for (int bb = 0; bb < CL; bb += PF) {
            f32x4 n[PF];
            if (bb + PF < CL) {
#pragma unroll
                for (int k = 0; k < PF; ++k)
                    n[k] = ld4(xb + (size_t)(bb + PF + k) * DG);
            }
#pragma unroll
            for (int k = 0; k < PF; ++k) {
                h = sclamp4(A1 * h + v[k]);
                __builtin_nontemporal_store(
                    h, (f32x4*)(ob + (size_t)(bb + k) * DG));
            }
            if (bb + PF < CL) {
#pragma unroll
                for (int k = 0; k < PF; ++k) v[k] = n[k];
            }
        }
    }
}

extern "C" void kernel_launch(void* const* d_in, const int* in_sizes, int n_in,
                              void* d_out, int out_size, void* d_ws, size_t ws_size,
                              hipStream_t stream) {
    const float4* x4 = (const float4*)d_in[0];
    const float4* w4 = (const float4*)d_in[1];
    float4* o4 = (float4*)d_out;
    rnn_fused3<<<dim3(RB * NTL), dim3(TPB), 0, stream>>>(x4, w4, o4);
}

// Round 15
// 120.510 us; speedup vs baseline: 1.1524x; 1.1524x over previous
//
#include <hip/hip_runtime.h>

// SimpleDiagonalRNN: h_t = a*h_{t-1} + x_t, a = 1 - relu(w), x [8,4096,512] f32.
//
// Correctness model (stable since r0):
//  * a = 1 - relu(w) <= 1 always; ~2% of channels have a < -1 -> reference
//    diverges to +/-inf; pass criterion tolerates any FINITE value there
//    (failure mode is NaN from same-sign inf - inf). Output must be finite.
//  * Clamp at +/-1e15 on EVERY product/FMA: |a|<~5, all states <=1e15 ->
//    every intermediate <= ~2e30 << FLT_MAX. No inf formed -> no NaN.
//  * For contracting channels (|a|<=1) the clamp never fires -> all parallel
//    re-associations are exact mod FP rounding (r4/r8/r11-r14 all passed).
//
// Perf history / model:
//  * dur_us ~= 66-77us harness overhead (poison fills) + kernel.
//  * r8-r13: 52-54us at 2.4-2.9 TB/s. r13 killed spill theory (VGPR=36,
//    WRITE still +20MB). r14 (32ch=128B line tiles): WRITE CLEAN 65.5MB,
//    kernel 44-47us at ~3.0 TB/s, Occupancy 10-13% -- only 128 blocks.
//  * MEASURED per-CU streaming cap ~24 GB/s: r14 = 3.0TB/s/128CU, fills =
//    6.3TB/s/256CU. We are at the per-CU rate with HALF the CUs idle.
//  * r15 (this): 256 blocks = (b, tile32, HALF of t). Cross-half dependency
//    (128B state at t=2047) is RECOMPUTED by half-1 blocks via an extra
//    aggregate-only parallel scan (P0) of the foreign half -- no sync, no
//    second dispatch. bid = h*128+p puts both halves on the same XCD
//    (128%8==0), so P0's reads share L2 lines with the twin's P1 fetch:
//    HBM read stays ~64MB. Carry folds into P2: WC = W_in + M^q*C0.

#define RB 8
#define RT 4096
#define RD 512
#define DG (RD / 4)      // 128 float4 groups over d
#define TG 8             // float4 groups per tile (32 ch = 128B = 1 line)
#define NTL (DG / TG)    // 16 tiles
#define HT (RT / 2)      // 2048 steps per half
#define CL 16            // timesteps per chunk
#define NC (HT / CL)     // 128 chunks per half-block
#define TPB 1024         // 16 waves
#define PF 4             // prefetch batch
#define HB 1e15f

typedef float f32x4 __attribute__((ext_vector_type(4)));

__device__ __forceinline__ float sclamp(float v) {
    return fminf(fmaxf(v, -HB), HB);
}
__device__ __forceinline__ f32x4 sclamp4(f32x4 v) {
    v.x = sclamp(v.x); v.y = sclamp(v.y);
    v.z = sclamp(v.z); v.w = sclamp(v.w);
    return v;
}
__device__ __forceinline__ f32x4 ld4(const float4* __restrict__ p) {
    return *(const f32x4* __restrict__)p;
}
__device__ __forceinline__ f32x4 shfl4(f32x4 v, int src) {
    f32x4 r;
    r.x = __shfl(v.x, src, 64);
    r.y = __shfl(v.y, src, 64);
    r.z = __shfl(v.z, src, 64);
    r.w = __shfl(v.w, src, 64);
    return r;
}
__device__ __forceinline__ f32x4 relu_decay(float4 wq) {
    f32x4 a;
    a.x = 1.0f - fmaxf(wq.x, 0.0f);
    a.y = 1.0f - fmaxf(wq.y, 0.0f);
    a.z = 1.0f - fmaxf(wq.z, 0.0f);
    a.w = 1.0f - fmaxf(wq.w, 0.0f);
    return a;
}

// PF-pipelined aggregate-only scan of one CL-step chunk at stride DG.
__device__ __forceinline__ f32x4 chunk_scan(const float4* __restrict__ xb,
                                            f32x4 A1) {
    f32x4 v[PF];
#pragma unroll
    for (int k = 0; k < PF; ++k) v[k] = ld4(xb + (size_t)k * DG);
    f32x4 h = {0.f, 0.f, 0.f, 0.f};
#pragma unroll
    for (int bb = 0; bb < CL; bb += PF) {
        f32x4 n[PF];
        if (bb + PF < CL) {              // compile-time (fully unrolled)
#pragma unroll
            for (int k = 0; k < PF; ++k)
                n[k] = ld4(xb + (size_t)(bb + PF + k) * DG);
        }
#pragma unroll
        for (int k = 0; k < PF; ++k) h = sclamp4(A1 * h + v[k]);
        if (bb + PF < CL) {
#pragma unroll
            for (int k = 0; k < PF; ++k) v[k] = n[k];
        }
    }
    return h;
}

// Block = (b, 32-ch tile, t-half). 1024 threads (16 waves).
// Thread map (P0/P1/P3): g = tid&7, c = tid>>3 (chunk 0..127).
// 8-lane cluster (g=0..7, fixed c) = 128B contiguous = 1 full cache line.
__global__ void __launch_bounds__(TPB, 4)
rnn_half(const float4* __restrict__ x4, const float4* __restrict__ w4,
         float4* __restrict__ out4) {
    const int tid = threadIdx.x;
    const int g   = tid & (TG - 1);
    const int c   = tid >> 3;            // 0..127

    const int bid  = blockIdx.x;
    const int hh   = bid >> 7;           // half 0..1
    const int p    = bid & 127;
    const int b    = p >> 4;             // 0..7
    const int tile = p & (NTL - 1);      // 0..15

    const f32x4 A1 = relu_decay(w4[tile * TG + g]);

    // LDS: padded *9 to break bank alignment.
    __shared__ f32x4 Wagg[NC * 9];       // chunk aggregates   [c*9+g]
    __shared__ f32x4 CI[NC * 9];         // chunk carry-ins    [c*9+g]
    __shared__ f32x4 WinAgg[2 * 9];      // window aggregates  [q*9+g]
    __shared__ f32x4 Hc[TG];             // carry into own half, per group

    const size_t tilebase = (size_t)b * RT * DG + (size_t)(tile * TG + g);
    const float4* __restrict__ xb_own =
        x4 + tilebase + (size_t)(hh * HT + c * CL) * DG;

    // P2/P0 wave mapping: w = tid>>6, g2 = w&7, q = w>>3, cc = q*64 + l.
    const int w  = tid >> 6;
    const int l  = tid & 63;
    const int g2 = w & (TG - 1);
    const int q  = w >> 3;
    const int cc = q * 64 + l;

    // B = a^CL = a^16 for group g2 (4 squarings); used in P0 and P2.
    f32x4 Bg2 = relu_decay(w4[tile * TG + g2]);
#pragma unroll
    for (int i = 0; i < 4; ++i) Bg2 = sclamp4(Bg2 * Bg2);

    // ---- P0 (half 1 only): recompute carry-in = aggregate of first half.
    // Reads are L2-shared with the co-XCD twin block's P1 fetch.
    if (hh == 1) {
        const float4* __restrict__ xb_f =
            x4 + tilebase + (size_t)(c * CL) * DG;
        Wagg[c * 9 + g] = chunk_scan(xb_f, A1);
        __syncthreads();
        {
            f32x4 S = Wagg[cc * 9 + g2];
            f32x4 M = Bg2;
#pragma unroll
            for (int s = 1; s < 64; s <<= 1) {
                f32x4 t = shfl4(S, l >= s ? l - s : l);
                S = (l >= s) ? sclamp4(M * t + S) : S;
                M = sclamp4(M * M);
            }
            if (l == 63) WinAgg[q * 9 + g2] = S;
            __syncthreads();
            // Total aggregate = state after chunk 127 (C0=0):
            // T_127 = S(q=1,l=63) + B^64 * WinAgg[0];  M == B^64 here.
            if (q == 1 && l == 63)
                Hc[g2] = sclamp4(M * WinAgg[0 * 9 + g2] + S);
        }
    }
    __syncthreads();   // (half 0: harmless extra barrier; block-uniform)

    // ---- P1: aggregate-only scan of own half's chunks ----
    Wagg[c * 9 + g] = chunk_scan(xb_own, A1);
    __syncthreads();

    // ---- P2: KS over 128 own aggregates, seeded with C0 ----
    {
        const f32x4 C0 = (hh == 1) ? Hc[g2]
                                   : (f32x4){0.f, 0.f, 0.f, 0.f};
        f32x4 S = Wagg[cc * 9 + g2];
        f32x4 M = Bg2;
#pragma unroll
        for (int s = 1; s < 64; s <<= 1) {
            f32x4 t = shfl4(S, l >= s ? l - s : l);
            S = (l >= s) ? sclamp4(M * t + S) : S;
            M = sclamp4(M * M);
        }
        // M = B^64 (window multiplier).
        if (l == 63) WinAgg[q * 9 + g2] = S;
        __syncthreads();

        // Effective window carry: WC = W_in + M^q * C0.
        f32x4 WC = C0;
        if (q == 1) WC = sclamp4(M * C0 + WinAgg[0 * 9 + g2]);
        // P = B^(l+1), l+1 in [1,64].
        const int n = l + 1;
        f32x4 P = {1.f, 1.f, 1.f, 1.f};
        f32x4 mm = Bg2;
#pragma unroll
        for (int k = 0; k < 7; ++k) {
            if ((n >> k) & 1) P = sclamp4(P * mm);
            mm = sclamp4(mm * mm);
        }
        f32x4 Sf = sclamp4(S + P * WC);      // true state after chunk cc
        if (cc < NC - 1) CI[(cc + 1) * 9 + g2] = Sf;
        if (cc == 0)     CI[0 * 9 + g2] = C0;
    }
    __syncthreads();

    // ---- P3: replay own chunk from (L2-hot) x with true carry-in ----
    {
        float4* __restrict__ ob =
            out4 + tilebase + (size_t)(hh * HT + c * CL) * DG;
        f32x4 h = CI[c * 9 + g];
        f32x4 v[PF];
#pragma unroll
        for (int k = 0; k < PF; ++k) v[k] = ld4(xb_own + (size_t)k * DG);
#pragma unroll
        for (int bb = 0; bb < CL; bb += PF) {
            f32x4 n[PF];
            if (bb + PF < CL) {
#pragma unroll
                for (int k = 0; k < PF; ++k)
                    n[k] = ld4(xb_own + (size_t)(bb + PF + k) * DG);
            }
#pragma unroll
            for (int k = 0; k < PF; ++k) {
                h = sclamp4(A1 * h + v[k]);
                __builtin_nontemporal_store(
                    h, (f32x4*)(ob + (size_t)(bb + k) * DG));
            }
            if (bb + PF < CL) {
#pragma unroll
                for (int k = 0; k < PF; ++k) v[k] = n[k];
            }
        }
    }
}

extern "C" void kernel_launch(void* const* d_in, const int* in_sizes, int n_in,
                              void* d_out, int out_size, void* d_ws, size_t ws_size,
                              hipStream_t stream) {
    const float4* x4 = (const float4*)d_in[0];
    const float4* w4 = (const float4*)d_in[1];
    float4* o4 = (float4*)d_out;
    rnn_half<<<dim3(2 * RB * NTL), dim3(TPB), 0, stream>>>(x4, w4, o4);
}